// Round 10
// baseline (280.327 us; speedup 1.0000x reference)
//
#include <hip/hip_runtime.h>
#include <hip/hip_bf16.h>

#define NH 12
#define SEQ 4096
#define E 768
#define DK 64

typedef float f32x4 __attribute__((ext_vector_type(4)));
typedef float f32x16 __attribute__((ext_vector_type(16)));
typedef __bf16 bf16x8 __attribute__((ext_vector_type(8)));
typedef __bf16 bf16x4 __attribute__((ext_vector_type(4)));
typedef unsigned u32x2 __attribute__((ext_vector_type(2)));
typedef unsigned u32x4 __attribute__((ext_vector_type(4)));

#define MFMA16(a, b, c) __builtin_amdgcn_mfma_f32_16x16x32_bf16((a), (b), (c), 0, 0, 0)
#define MFMA32(a, b, c) __builtin_amdgcn_mfma_f32_32x32x16_bf16((a), (b), (c), 0, 0, 0)

// log2(e) / sqrt(dk); folded into K weights at wsplit time.
#define SCL 0.18033688011112042f
// defer-max threshold in log2 units: P bounded by 2^10.8
#define DEFER 10.8f

__device__ __forceinline__ void gload16(const void* g, void* l) {
    __builtin_amdgcn_global_load_lds(
        (const __attribute__((address_space(1))) void*)g,
        (__attribute__((address_space(3))) void*)l, 16, 0, 0);
}

__device__ __forceinline__ void block_sync() {
    __builtin_amdgcn_sched_barrier(0);
    __builtin_amdgcn_s_barrier();
    __builtin_amdgcn_sched_barrier(0);
}

__device__ __forceinline__ unsigned cvtpk(float lo, float hi) {
    unsigned r;
    asm("v_cvt_pk_bf16_f32 %0, %1, %2" : "=v"(r) : "v"(lo), "v"(hi));
    return r;
}
__device__ __forceinline__ u32x2 plswap(unsigned a, unsigned b) {
    return __builtin_amdgcn_permlane32_swap(a, b, false, false);
}
__device__ __forceinline__ float xhalf_max(float v) {
    u32x2 r = plswap(__float_as_uint(v), __float_as_uint(v));
    return fmaxf(__uint_as_float(r.x), __uint_as_float(r.y));
}
__device__ __forceinline__ float xhalf_add(float v) {
    u32x2 r = plswap(__float_as_uint(v), __float_as_uint(v));
    return __uint_as_float(r.x) + __uint_as_float(r.y);
}

// ---------------------------------------------------------------------------
// Kernel 0: split x into bf16 hi/lo
// ---------------------------------------------------------------------------
__global__ __launch_bounds__(256) void xsplit_kernel(const float* __restrict__ x,
                                                     __bf16* __restrict__ xh,
                                                     __bf16* __restrict__ xl) {
    int i = blockIdx.x * blockDim.x + threadIdx.x;
    float4 v = ((const float4*)x)[i];
    bf16x4 h, l;
    float vv[4] = {v.x, v.y, v.z, v.w};
#pragma unroll
    for (int j = 0; j < 4; ++j) {
        __bf16 hh = (__bf16)vv[j];
        h[j] = hh;
        l[j] = (__bf16)(vv[j] - (float)hh);
    }
    ((bf16x4*)xh)[i] = h;
    ((bf16x4*)xl)[i] = l;
}

// ---------------------------------------------------------------------------
// Kernel 1: split projection weights (hi/lo), transpose to [h][n][k].
// K weights pre-scaled by SCL so attention scores come out in log2 units.
// ---------------------------------------------------------------------------
__global__ void wsplit_kernel(const float* __restrict__ qp,
                              const float* __restrict__ kp,
                              const float* __restrict__ vp,
                              __bf16* __restrict__ wtq_h, __bf16* __restrict__ wtq_l,
                              __bf16* __restrict__ wtk_h, __bf16* __restrict__ wtk_l,
                              __bf16* __restrict__ wtv_h) {
    int idx = blockIdx.x * blockDim.x + threadIdx.x;
    if (idx >= NH * E * DK) return;
    int h = idx / (E * DK);
    int rem = idx - h * E * DK;
    int k = rem / DK;
    int n = rem - k * DK;
    int o = h * DK * E + n * E + k;  // [h][n][k]
    float q = qp[idx];
    __bf16 qh = (__bf16)q;
    wtq_h[o] = qh;
    wtq_l[o] = (__bf16)(q - (float)qh);
    float kk = kp[idx] * SCL;
    __bf16 kh = (__bf16)kk;
    wtk_h[o] = kh;
    wtk_l[o] = (__bf16)(kk - (float)kh);
    wtv_h[o] = (__bf16)vp[idx];
}

// ---------------------------------------------------------------------------
// Kernel 2a: fused Q+K projection. Block = 128 rows x 1 head, 4 waves x 32
// rows (rt=2). Wq/Wk hi+lo staged in LDS (dbuf, counted vmcnt); x read once.
// ---------------------------------------------------------------------------
__global__ __launch_bounds__(256, 2) void proj_qk_kernel(
    const __bf16* __restrict__ xh, const __bf16* __restrict__ xl,
    const __bf16* __restrict__ wq_h_g, const __bf16* __restrict__ wq_l_g,
    const __bf16* __restrict__ wk_h_g, const __bf16* __restrict__ wk_l_g,
    __bf16* __restrict__ qh_o, __bf16* __restrict__ ql_o,
    __bf16* __restrict__ kh_o, __bf16* __restrict__ kl_o) {
    __shared__ char wlds[2][16384];  // [buf][ Wqh 4K | Wql 4K | Wkh 4K | Wkl 4K ]

    const int wg = (blockIdx.x & 7) * 48 + (blockIdx.x >> 3);  // 384 = 8 x 48
    const int head = wg >> 5;  // /32
    const int rb = wg & 31;    // 0..31
    const int wave = threadIdx.x >> 6;
    const int lane = threadIdx.x & 63;
    const int lrow = lane & 15;
    const int lk8 = (lane >> 4) * 8;
    const int g4 = (lane >> 4) * 4;
    const int rowbase = rb * 128 + wave * 32;

    const char* wq_h_b = (const char*)(wq_h_g + head * DK * E);
    const char* wq_l_b = (const char*)(wq_l_g + head * DK * E);
    const char* wk_h_b = (const char*)(wk_h_g + head * DK * E);
    const char* wk_l_b = (const char*)(wk_l_g + head * DK * E);
    const char* base = (wave == 0) ? wq_h_b : (wave == 1) ? wq_l_b
                      : (wave == 2) ? wk_h_b : wk_l_b;
    const int srow = lane >> 2;        // 0..15
    const int scol = (lane & 3) * 16;  // byte in 64B row-slice

    auto STAGE = [&](int buf, int ks) {
#pragma unroll
        for (int r = 0; r < 4; ++r) {
            const char* src = base + (size_t)(r * 16 + srow) * (E * 2) + ks * 64 + scol;
            gload16(src, wlds[buf] + (wave * 4 + r) * 1024 + lane * 16);
        }
    };

    f32x4 accq[2][4], acck[2][4];
#pragma unroll
    for (int rt = 0; rt < 2; ++rt)
#pragma unroll
        for (int f = 0; f < 4; ++f) {
            accq[rt][f] = (f32x4){0.f, 0.f, 0.f, 0.f};
            acck[rt][f] = (f32x4){0.f, 0.f, 0.f, 0.f};
        }

    bf16x8 ah[2], al[2], ahn[2], aln[2];
    auto LOADA = [&](int ks, bf16x8* h, bf16x8* l) {
#pragma unroll
        for (int rt = 0; rt < 2; ++rt) {
            size_t xo = (size_t)(rowbase + rt * 16 + lrow) * E + ks * 32 + lk8;
            h[rt] = *(const bf16x8*)(xh + xo);
            l[rt] = *(const bf16x8*)(xl + xo);
        }
    };

    LOADA(0, ah, al);
    STAGE(0, 0);
    int buf = 0;
    for (int ks = 0; ks < 24; ++ks) {
        if (ks < 23) {
            LOADA(ks + 1, ahn, aln);
            STAGE(buf ^ 1, ks + 1);
            asm volatile("s_waitcnt vmcnt(8)" ::: "memory");
        } else {
            asm volatile("s_waitcnt vmcnt(0)" ::: "memory");
        }
        block_sync();
#pragma unroll
        for (int f = 0; f < 4; ++f) {
            int bo = (f * 16 + lrow) * 64 + lk8 * 2;
            bf16x8 bqh = *(const bf16x8*)(wlds[buf] + bo);
            bf16x8 bql = *(const bf16x8*)(wlds[buf] + 4096 + bo);
            bf16x8 bkh = *(const bf16x8*)(wlds[buf] + 8192 + bo);
            bf16x8 bkl = *(const bf16x8*)(wlds[buf] + 12288 + bo);
#pragma unroll
            for (int rt = 0; rt < 2; ++rt) {
                accq[rt][f] = MFMA16(ah[rt], bqh, accq[rt][f]);
                accq[rt][f] = MFMA16(ah[rt], bql, accq[rt][f]);
                accq[rt][f] = MFMA16(al[rt], bqh, accq[rt][f]);
                acck[rt][f] = MFMA16(ah[rt], bkh, acck[rt][f]);
                acck[rt][f] = MFMA16(ah[rt], bkl, acck[rt][f]);
                acck[rt][f] = MFMA16(al[rt], bkh, acck[rt][f]);
            }
        }
        block_sync();
        if (ks < 23) {
#pragma unroll
            for (int rt = 0; rt < 2; ++rt) {
                ah[rt] = ahn[rt];
                al[rt] = aln[rt];
            }
        }
        buf ^= 1;
    }

#pragma unroll
    for (int rt = 0; rt < 2; ++rt)
#pragma unroll
        for (int f = 0; f < 4; ++f)
#pragma unroll
            for (int r = 0; r < 4; ++r) {
                int srow_o = rowbase + rt * 16 + g4 + r;
                int d = f * 16 + lrow;
                size_t o = (size_t)head * SEQ * DK + (size_t)srow_o * DK + d;
                float qv = accq[rt][f][r];
                __bf16 qhh = (__bf16)qv;
                qh_o[o] = qhh;
                ql_o[o] = (__bf16)(qv - (float)qhh);
                float kv = acck[rt][f][r];
                __bf16 khh = (__bf16)kv;
                kh_o[o] = khh;
                kl_o[o] = (__bf16)(kv - (float)khh);
            }
}

// ---------------------------------------------------------------------------
// Kernel 2b: V projection (1-term, operand-swapped -> coalesced V^T stores).
// ---------------------------------------------------------------------------
__global__ __launch_bounds__(256) void proj_v_kernel(
    const __bf16* __restrict__ xh, const __bf16* __restrict__ w_v,
    __bf16* __restrict__ vt_o) {
    __shared__ char wlds[2][4096];

    const int wg = (blockIdx.x & 7) * 48 + (blockIdx.x >> 3);
    const int head = wg >> 5;
    const int rb = wg & 31;
    const int wave = threadIdx.x >> 6;
    const int lane = threadIdx.x & 63;
    const int lrow = lane & 15;
    const int lk8 = (lane >> 4) * 8;
    const int g4 = (lane >> 4) * 4;
    const int rowbase = rb * 128 + wave * 32;

    const char* wv_b = (const char*)(w_v + head * DK * E);
    const int srow = lane >> 2;
    const int scol = (lane & 3) * 16;

    auto STAGE = [&](int buf, int ks) {
        const char* src = wv_b + (size_t)(wave * 16 + srow) * (E * 2) + ks * 64 + scol;
        gload16(src, wlds[buf] + wave * 1024 + lane * 16);
    };

    f32x4 acc[2][4];
#pragma unroll
    for (int rt = 0; rt < 2; ++rt)
#pragma unroll
        for (int f = 0; f < 4; ++f) acc[rt][f] = (f32x4){0.f, 0.f, 0.f, 0.f};

    bf16x8 ah[2], ahn[2];
    auto LOADA = [&](int ks, bf16x8* h) {
#pragma unroll
        for (int rt = 0; rt < 2; ++rt) {
            size_t xo = (size_t)(rowbase + rt * 16 + lrow) * E + ks * 32 + lk8;
            h[rt] = *(const bf16x8*)(xh + xo);
        }
    };

    LOADA(0, ah);
    STAGE(0, 0);
    int buf = 0;
    for (int ks = 0; ks < 24; ++ks) {
        if (ks < 23) {
            LOADA(ks + 1, ahn);
            STAGE(buf ^ 1, ks + 1);
            asm volatile("s_waitcnt vmcnt(3)" ::: "memory");
        } else {
            asm volatile("s_waitcnt vmcnt(0)" ::: "memory");
        }
        block_sync();
#pragma unroll
        for (int f = 0; f < 4; ++f) {
            int bo = (f * 16 + lrow) * 64 + lk8 * 2;
            bf16x8 bv = *(const bf16x8*)(wlds[buf] + bo);
#pragma unroll
            for (int rt = 0; rt < 2; ++rt)
                acc[rt][f] = MFMA16(bv, ah[rt], acc[rt][f]);  // D[d][s]
        }
        block_sync();
        if (ks < 23) {
#pragma unroll
            for (int rt = 0; rt < 2; ++rt) ah[rt] = ahn[rt];
        }
        buf ^= 1;
    }

#pragma unroll
    for (int rt = 0; rt < 2; ++rt)
#pragma unroll
        for (int f = 0; f < 4; ++f)
#pragma unroll
            for (int r = 0; r < 4; ++r) {
                int vd = f * 16 + g4 + r;
                int vs = rowbase + rt * 16 + lrow;
                vt_o[(size_t)head * DK * SEQ + (size_t)vd * SEQ + vs] = (__bf16)acc[rt][f][r];
            }
}

// ---------------------------------------------------------------------------
// Kernel 3: causal flash attention — split-KV x4, barrier-free main loop.
// Block = 256 thr = 4 independent waves on ONE 32-row q-window; wave i does
// tiles i, i+4, ... (interleaved -> balanced under causality). K(hi,lo)/V^T
// read directly from global (L2-resident, XCD-chunked). Swapped 32x32x16
// MFMA, in-register softmax/P, defer-max. End: LDS flash-combine of the 4
// partials (2 syncthreads). 1536 blocks, heavy-first.
// launch_bounds (256,2): VGPR cap 256. History: (256,6) capped at 85 ->
// massive spill (938 MB scratch writes, r8); (256,4) capped at 128 but the
// compiler squeezed to the 64-VGPR tier and STILL spilled the f32x16
// accumulators (r9: VGPR=64 < the 80 this body needs, +4.5 MB HBM writes).
// (256,2) lets it allocate the ~100-128 it actually needs, zero spill.
// ---------------------------------------------------------------------------
__global__ __launch_bounds__(256, 2) void attn_kernel(
    const __bf16* __restrict__ qh, const __bf16* __restrict__ ql,
    const __bf16* __restrict__ kh, const __bf16* __restrict__ kl,
    const __bf16* __restrict__ vt,
    float* __restrict__ out) {
    __shared__ float cbuf[3][64][33];  // waves 1..3 rescaled O partials (bank-safe)
    __shared__ float mlb[4][2][32];    // [wave][0=m,1=l'][row]

    const int wg = (blockIdx.x & 7) * 192 + (blockIdx.x >> 3);  // 1536 = 8 x 192
    const int head = wg >> 7;               // 0..11
    const int window = 127 - (wg & 127);    // heavy-first
    const int rowbase = window * 32;
    const int wave = threadIdx.x >> 6;
    const int lane = threadIdx.x & 63;
    const int lq = lane & 31;
    const int lh = lane >> 5;

    const size_t hoff = (size_t)head * SEQ * DK;

    // Q B-frags: lane holds Q[rowbase+lq][ds*16 + lh*8 + 0..7]
    bf16x8 qBh[4], qBl[4];
    {
        const __bf16* qph = qh + hoff + (size_t)(rowbase + lq) * DK + lh * 8;
        const __bf16* qpl = ql + hoff + (size_t)(rowbase + lq) * DK + lh * 8;
#pragma unroll
        for (int ds = 0; ds < 4; ++ds) {
            qBh[ds] = *(const bf16x8*)(qph + ds * 16);
            qBl[ds] = *(const bf16x8*)(qpl + ds * 16);
        }
    }

    // per-tile walking pointers, offset to this wave's first tile (stride 4)
    const char* kh_p = (const char*)(kh + hoff) + wave * 8192 + lq * 128 + lh * 16;
    const char* kl_p = (const char*)(kl + hoff) + wave * 8192 + lq * 128 + lh * 16;
    const char* vt_pa = (const char*)(vt + (size_t)head * DK * SEQ)
                        + (size_t)lq * (SEQ * 2) + wave * 128 + lh * 16;
    const char* vt_pb = vt_pa + (size_t)32 * (SEQ * 2);

    f32x16 O0 = (f32x16)0.0f, O1 = (f32x16)0.0f;
    float m = -3.0e38f, lsum = 0.f;

    const int nt = (window >> 1) + 1;

    for (int t = wave; t < nt; t += 4) {
        const int kb = t * 64;

        // ---- S = K'^T Q (log2 units). s0: keys kb..kb+31, s1: +32..63 ----
        f32x16 s0 = (f32x16)0.0f, s1 = (f32x16)0.0f;
#pragma unroll
        for (int ds = 0; ds < 4; ++ds) {
            bf16x8 ah0 = *(const bf16x8*)(kh_p + ds * 32);
            bf16x8 al0 = *(const bf16x8*)(kl_p + ds * 32);
            bf16x8 ah1 = *(const bf16x8*)(kh_p + 4096 + ds * 32);
            bf16x8 al1 = *(const bf16x8*)(kl_p + 4096 + ds * 32);
            s0 = MFMA32(ah0, qBh[ds], s0);
            s1 = MFMA32(ah1, qBh[ds], s1);
            s0 = MFMA32(al0, qBh[ds], s0);
            s1 = MFMA32(al1, qBh[ds], s1);
            s0 = MFMA32(ah0, qBl[ds], s0);
            s1 = MFMA32(ah1, qBl[ds], s1);
        }

        // ---- causal mask (only the diagonal tile triggers) ----
        if (kb + 63 > rowbase) {
            int qa = rowbase + lq;
#pragma unroll
            for (int r = 0; r < 16; ++r) {
                int kp = kb + ((r & 3) + 8 * (r >> 2) + 4 * lh);
                if (kp > qa) s0[r] = -1.0e30f;
                if (kp + 32 > qa) s1[r] = -1.0e30f;
            }
        }

        // ---- row max: 4-chain tree + one cross-half swap ----
        float x0 = fmaxf(s0[0], s0[1]), x1 = fmaxf(s0[2], s0[3]);
        float x2 = fmaxf(s0[4], s0[5]), x3 = fmaxf(s0[6], s0[7]);
#pragma unroll
        for (int r = 8; r < 16; r += 4) {
            x0 = fmaxf(x0, fmaxf(s0[r], s0[r + 1]));
            x1 = fmaxf(x1, fmaxf(s0[r + 2], s0[r + 3]));
        }
#pragma unroll
        for (int r = 0; r < 16; r += 4) {
            x2 = fmaxf(x2, fmaxf(s1[r], s1[r + 1]));
            x3 = fmaxf(x3, fmaxf(s1[r + 2], s1[r + 3]));
        }
        float mx = xhalf_max(fmaxf(fmaxf(x0, x1), fmaxf(x2, x3)));

        // ---- defer-max rescale (rare); alpha broadcast via shfl ----
        if (!__all(mx - m <= DEFER)) {
            float mn = fmaxf(m, mx);
            float al = exp2f(m - mn);
            m = mn;
            lsum *= al;
#pragma unroll
            for (int r = 0; r < 16; ++r) {
                float a = __shfl(al, (r & 3) + 8 * (r >> 2) + 4 * lh);
                O0[r] *= a;
                O1[r] *= a;
            }
        }

        // ---- P = exp2(S - m); l accumulation ----
#pragma unroll
        for (int r = 0; r < 16; ++r) {
            s0[r] = exp2f(s0[r] - m);
            s1[r] = exp2f(s1[r] - m);
        }
        {
            float p0 = 0.f, p1 = 0.f, p2 = 0.f, p3 = 0.f;
#pragma unroll
            for (int r = 0; r < 16; r += 4) {
                p0 += s0[r] + s0[r + 1];
                p1 += s0[r + 2] + s0[r + 3];
                p2 += s1[r] + s1[r + 1];
                p3 += s1[r + 2] + s1[r + 3];
            }
            lsum += (p0 + p1) + (p2 + p3);
        }

        // ---- P -> PV A-frags: cvt_pk + permlane32_swap (in-register) ----
        unsigned W0 = cvtpk(s0[0], s0[1]), W1 = cvtpk(s0[2], s0[3]);
        unsigned W2 = cvtpk(s0[4], s0[5]), W3 = cvtpk(s0[6], s0[7]);
        unsigned W4 = cvtpk(s0[8], s0[9]), W5 = cvtpk(s0[10], s0[11]);
        unsigned W6 = cvtpk(s0[12], s0[13]), W7 = cvtpk(s0[14], s0[15]);
        u32x2 rA = plswap(W0, W2), rB = plswap(W1, W3);
        u32x2 rC = plswap(W4, W6), rD = plswap(W5, W7);
        bf16x8 p00 = __builtin_bit_cast(bf16x8, (u32x4){rA.x, rB.x, rA.y, rB.y});
        bf16x8 p01 = __builtin_bit_cast(bf16x8, (u32x4){rC.x, rD.x, rC.y, rD.y});
        W0 = cvtpk(s1[0], s1[1]); W1 = cvtpk(s1[2], s1[3]);
        W2 = cvtpk(s1[4], s1[5]); W3 = cvtpk(s1[6], s1[7]);
        W4 = cvtpk(s1[8], s1[9]); W5 = cvtpk(s1[10], s1[11]);
        W6 = cvtpk(s1[12], s1[13]); W7 = cvtpk(s1[14], s1[15]);
        rA = plswap(W0, W2); rB = plswap(W1, W3);
        rC = plswap(W4, W6); rD = plswap(W5, W7);
        bf16x8 p10 = __builtin_bit_cast(bf16x8, (u32x4){rA.x, rB.x, rA.y, rB.y});
        bf16x8 p11 = __builtin_bit_cast(bf16x8, (u32x4){rC.x, rD.x, rC.y, rD.y});

        // ---- O += P V (B-frags direct from global V^T) ----
        {
            bf16x8 v00 = *(const bf16x8*)(vt_pa + 0);
            bf16x8 v01 = *(const bf16x8*)(vt_pa + 32);
            bf16x8 v10 = *(const bf16x8*)(vt_pa + 64);
            bf16x8 v11 = *(const bf16x8*)(vt_pa + 96);
            O0 = MFMA32(p00, v00, O0);
            O0 = MFMA32(p01, v01, O0);
            O0 = MFMA32(p10, v10, O0);
            O0 = MFMA32(p11, v11, O0);
            bf16x8 w00 = *(const bf16x8*)(vt_pb + 0);
            bf16x8 w01 = *(const bf16x8*)(vt_pb + 32);
            bf16x8 w10 = *(const bf16x8*)(vt_pb + 64);
            bf16x8 w11 = *(const bf16x8*)(vt_pb + 96);
            O1 = MFMA32(p00, w00, O1);
            O1 = MFMA32(p01, w01, O1);
            O1 = MFMA32(p10, w10, O1);
            O1 = MFMA32(p11, w11, O1);
        }

        kh_p += 4 * 64 * 128;   // next owned tile (stride 4)
        kl_p += 4 * 64 * 128;
        vt_pa += 4 * 128;
        vt_pb += 4 * 128;
    }

    // ---- combine the 4 split-KV partials (flash merge in LDS) ----
    // 1) publish per-row m
    if (lh == 0) mlb[wave][0][lq] = m;
    __syncthreads();
    float mstar = fmaxf(fmaxf(mlb[0][0][lq], mlb[1][0][lq]),
                        fmaxf(mlb[2][0][lq], mlb[3][0][lq]));
    // 2) rescale own partial; idle waves (m=-inf) contribute exactly 0
    float sc = exp2f(m - mstar);
    float lp = xhalf_add(lsum) * sc;
#pragma unroll
    for (int r = 0; r < 16; ++r) {
        float a = __shfl(sc, (r & 3) + 8 * (r >> 2) + 4 * lh);
        O0[r] *= a;
        O1[r] *= a;
    }
    if (wave > 0) {
        if (lh == 0) mlb[wave][1][lq] = lp;
        float* cb = &cbuf[wave - 1][lane][0];
#pragma unroll
        for (int r = 0; r < 16; ++r) {
            cb[r] = O0[r];
            cb[16 + r] = O1[r];
        }
    }
    __syncthreads();
    if (wave == 0) {
        float ltot = lp + mlb[1][1][lq] + mlb[2][1][lq] + mlb[3][1][lq];
#pragma unroll
        for (int i = 0; i < 3; ++i) {
            const float* cb = &cbuf[i][lane][0];
#pragma unroll
            for (int r = 0; r < 16; ++r) {
                O0[r] += cb[r];
                O1[r] += cb[16 + r];
            }
        }
        float linv = 1.0f / ltot;
#pragma unroll
        for (int r = 0; r < 16; ++r) {
            int rr = (r & 3) + 8 * (r >> 2) + 4 * lh;
            float li = __shfl(linv, rr);
            size_t o = hoff + (size_t)(rowbase + rr) * DK + lq;
            out[o] = O0[r] * li;
            out[o + 32] = O1[r] * li;
        }
    }
}

// ---------------------------------------------------------------------------
extern "C" void kernel_launch(void* const* d_in, const int* in_sizes, int n_in,
                              void* d_out, int out_size, void* d_ws, size_t ws_size,
                              hipStream_t stream) {
    const float* x = (const float*)d_in[0];
    const float* qp = (const float*)d_in[1];
    const float* kp = (const float*)d_in[2];
    const float* vp = (const float*)d_in[3];
    float* out = (float*)d_out;

    const size_t WT_SZ = (size_t)NH * DK * E * 2;     // 1,179,648 B
    const size_t QKV_SZ = (size_t)NH * SEQ * DK * 2;  // 6,291,456 B
    const size_t X_SZ = (size_t)SEQ * E * 2;          // 6,291,456 B
    char* ws = (char*)d_ws;
    __bf16* wtq_h = (__bf16*)(ws + 0 * WT_SZ);
    __bf16* wtq_l = (__bf16*)(ws + 1 * WT_SZ);
    __bf16* wtk_h = (__bf16*)(ws + 2 * WT_SZ);
    __bf16* wtk_l = (__bf16*)(ws + 3 * WT_SZ);
    __bf16* wtv_h = (__bf16*)(ws + 4 * WT_SZ);
    char* p2 = ws + 5 * WT_SZ;
    __bf16* qh = (__bf16*)(p2 + 0 * QKV_SZ);
    __bf16* ql = (__bf16*)(p2 + 1 * QKV_SZ);
    __bf16* kh = (__bf16*)(p2 + 2 * QKV_SZ);
    __bf16* kl = (__bf16*)(p2 + 3 * QKV_SZ);
    __bf16* vt = (__bf16*)(p2 + 4 * QKV_SZ);
    char* p3 = p2 + 5 * QKV_SZ;
    __bf16* xh = (__bf16*)(p3 + 0 * X_SZ);
    __bf16* xl = (__bf16*)(p3 + 1 * X_SZ);

    hipLaunchKernelGGL(xsplit_kernel, dim3(SEQ * E / 4 / 256), dim3(256), 0, stream,
                       x, xh, xl);
    hipLaunchKernelGGL(wsplit_kernel, dim3((NH * E * DK + 255) / 256), dim3(256), 0, stream,
                       qp, kp, vp, wtq_h, wtq_l, wtk_h, wtk_l, wtv_h);
    hipLaunchKernelGGL(proj_qk_kernel, dim3(384), dim3(256), 0, stream,
                       xh, xl, wtq_h, wtq_l, wtk_h, wtk_l, qh, ql, kh, kl);
    hipLaunchKernelGGL(proj_v_kernel, dim3(384), dim3(256), 0, stream,
                       xh, wtv_h, vt);
    hipLaunchKernelGGL(attn_kernel, dim3(1536), dim3(256), 0, stream,
                       qh, ql, kh, kl, vt, out);
}

// Round 11
// 181.998 us; speedup vs baseline: 1.5403x; 1.5403x over previous
//
#include <hip/hip_runtime.h>
#include <hip/hip_bf16.h>

#define NH 12
#define SEQ 4096
#define E 768
#define DK 64

typedef float f32x4 __attribute__((ext_vector_type(4)));
typedef float f32x16 __attribute__((ext_vector_type(16)));
typedef __bf16 bf16x8 __attribute__((ext_vector_type(8)));
typedef __bf16 bf16x4 __attribute__((ext_vector_type(4)));
typedef unsigned u32x2 __attribute__((ext_vector_type(2)));
typedef unsigned u32x4 __attribute__((ext_vector_type(4)));

#define MFMA16(a, b, c) __builtin_amdgcn_mfma_f32_16x16x32_bf16((a), (b), (c), 0, 0, 0)
#define MFMA32(a, b, c) __builtin_amdgcn_mfma_f32_32x32x16_bf16((a), (b), (c), 0, 0, 0)

// log2(e) / sqrt(dk); folded into K weights at wsplit time.
#define SCL 0.18033688011112042f
// defer-max threshold in log2 units: P bounded by 2^10.8
#define DEFER 10.8f

// Fragment-linear K layout (per head, per matrix): element (key, d) at byte
//   (key>>6)*8192 + ((key>>5)&1)*4096 + (d>>4)*1024
//   + ((key&31) + 32*((d>>3)&1))*16 + (d&7)*2
// so the attn A-frag load for (tile, half, ds) is base + lane*16 (1KB burst).
// Fragment-linear V layout: element (key, d) at byte
//   (key>>6)*8192 + ((d>>5)&1)*4096 + ((key>>4)&3)*1024
//   + ((d&31) + 32*((key>>3)&1))*16 + (key&7)*2
// so the PV B-frag load for (tile, dt, ks) is base + lane*16.

__device__ __forceinline__ void gload16(const void* g, void* l) {
    __builtin_amdgcn_global_load_lds(
        (const __attribute__((address_space(1))) void*)g,
        (__attribute__((address_space(3))) void*)l, 16, 0, 0);
}

__device__ __forceinline__ void block_sync() {
    __builtin_amdgcn_sched_barrier(0);
    __builtin_amdgcn_s_barrier();
    __builtin_amdgcn_sched_barrier(0);
}

__device__ __forceinline__ unsigned cvtpk(float lo, float hi) {
    unsigned r;
    asm("v_cvt_pk_bf16_f32 %0, %1, %2" : "=v"(r) : "v"(lo), "v"(hi));
    return r;
}
__device__ __forceinline__ u32x2 plswap(unsigned a, unsigned b) {
    return __builtin_amdgcn_permlane32_swap(a, b, false, false);
}
__device__ __forceinline__ float xhalf_max(float v) {
    u32x2 r = plswap(__float_as_uint(v), __float_as_uint(v));
    return fmaxf(__uint_as_float(r.x), __uint_as_float(r.y));
}
__device__ __forceinline__ float xhalf_add(float v) {
    u32x2 r = plswap(__float_as_uint(v), __float_as_uint(v));
    return __uint_as_float(r.x) + __uint_as_float(r.y);
}

// ---------------------------------------------------------------------------
// Kernel 0: split x into bf16 hi/lo
// ---------------------------------------------------------------------------
__global__ __launch_bounds__(256) void xsplit_kernel(const float* __restrict__ x,
                                                     __bf16* __restrict__ xh,
                                                     __bf16* __restrict__ xl) {
    int i = blockIdx.x * blockDim.x + threadIdx.x;
    float4 v = ((const float4*)x)[i];
    bf16x4 h, l;
    float vv[4] = {v.x, v.y, v.z, v.w};
#pragma unroll
    for (int j = 0; j < 4; ++j) {
        __bf16 hh = (__bf16)vv[j];
        h[j] = hh;
        l[j] = (__bf16)(vv[j] - (float)hh);
    }
    ((bf16x4*)xh)[i] = h;
    ((bf16x4*)xl)[i] = l;
}

// ---------------------------------------------------------------------------
// Kernel 1: split projection weights (hi/lo), transpose to [h][n][k].
// K weights pre-scaled by SCL so attention scores come out in log2 units.
// ---------------------------------------------------------------------------
__global__ void wsplit_kernel(const float* __restrict__ qp,
                              const float* __restrict__ kp,
                              const float* __restrict__ vp,
                              __bf16* __restrict__ wtq_h, __bf16* __restrict__ wtq_l,
                              __bf16* __restrict__ wtk_h, __bf16* __restrict__ wtk_l,
                              __bf16* __restrict__ wtv_h) {
    int idx = blockIdx.x * blockDim.x + threadIdx.x;
    if (idx >= NH * E * DK) return;
    int h = idx / (E * DK);
    int rem = idx - h * E * DK;
    int k = rem / DK;
    int n = rem - k * DK;
    int o = h * DK * E + n * E + k;  // [h][n][k]
    float q = qp[idx];
    __bf16 qh = (__bf16)q;
    wtq_h[o] = qh;
    wtq_l[o] = (__bf16)(q - (float)qh);
    float kk = kp[idx] * SCL;
    __bf16 kh = (__bf16)kk;
    wtk_h[o] = kh;
    wtk_l[o] = (__bf16)(kk - (float)kh);
    wtv_h[o] = (__bf16)vp[idx];
}

// ---------------------------------------------------------------------------
// Kernel 2a: fused Q+K projection. Block = 128 rows x 1 head, 4 waves x 32
// rows (rt=2). Wq/Wk hi+lo staged in LDS (dbuf, counted vmcnt); x read once.
// Q written row-major [h][s][d]; K written in FRAGMENT-LINEAR layout.
// ---------------------------------------------------------------------------
__global__ __launch_bounds__(256, 2) void proj_qk_kernel(
    const __bf16* __restrict__ xh, const __bf16* __restrict__ xl,
    const __bf16* __restrict__ wq_h_g, const __bf16* __restrict__ wq_l_g,
    const __bf16* __restrict__ wk_h_g, const __bf16* __restrict__ wk_l_g,
    __bf16* __restrict__ qh_o, __bf16* __restrict__ ql_o,
    __bf16* __restrict__ kh_o, __bf16* __restrict__ kl_o) {
    __shared__ char wlds[2][16384];  // [buf][ Wqh 4K | Wql 4K | Wkh 4K | Wkl 4K ]

    const int wg = (blockIdx.x & 7) * 48 + (blockIdx.x >> 3);  // 384 = 8 x 48
    const int head = wg >> 5;  // /32
    const int rb = wg & 31;    // 0..31
    const int wave = threadIdx.x >> 6;
    const int lane = threadIdx.x & 63;
    const int lrow = lane & 15;
    const int lk8 = (lane >> 4) * 8;
    const int g4 = (lane >> 4) * 4;
    const int rowbase = rb * 128 + wave * 32;

    const char* wq_h_b = (const char*)(wq_h_g + head * DK * E);
    const char* wq_l_b = (const char*)(wq_l_g + head * DK * E);
    const char* wk_h_b = (const char*)(wk_h_g + head * DK * E);
    const char* wk_l_b = (const char*)(wk_l_g + head * DK * E);
    const char* base = (wave == 0) ? wq_h_b : (wave == 1) ? wq_l_b
                      : (wave == 2) ? wk_h_b : wk_l_b;
    const int srow = lane >> 2;        // 0..15
    const int scol = (lane & 3) * 16;  // byte in 64B row-slice

    auto STAGE = [&](int buf, int ks) {
#pragma unroll
        for (int r = 0; r < 4; ++r) {
            const char* src = base + (size_t)(r * 16 + srow) * (E * 2) + ks * 64 + scol;
            gload16(src, wlds[buf] + (wave * 4 + r) * 1024 + lane * 16);
        }
    };

    f32x4 accq[2][4], acck[2][4];
#pragma unroll
    for (int rt = 0; rt < 2; ++rt)
#pragma unroll
        for (int f = 0; f < 4; ++f) {
            accq[rt][f] = (f32x4){0.f, 0.f, 0.f, 0.f};
            acck[rt][f] = (f32x4){0.f, 0.f, 0.f, 0.f};
        }

    bf16x8 ah[2], al[2], ahn[2], aln[2];
    auto LOADA = [&](int ks, bf16x8* h, bf16x8* l) {
#pragma unroll
        for (int rt = 0; rt < 2; ++rt) {
            size_t xo = (size_t)(rowbase + rt * 16 + lrow) * E + ks * 32 + lk8;
            h[rt] = *(const bf16x8*)(xh + xo);
            l[rt] = *(const bf16x8*)(xl + xo);
        }
    };

    LOADA(0, ah, al);
    STAGE(0, 0);
    int buf = 0;
    for (int ks = 0; ks < 24; ++ks) {
        if (ks < 23) {
            LOADA(ks + 1, ahn, aln);
            STAGE(buf ^ 1, ks + 1);
            asm volatile("s_waitcnt vmcnt(8)" ::: "memory");
        } else {
            asm volatile("s_waitcnt vmcnt(0)" ::: "memory");
        }
        block_sync();
#pragma unroll
        for (int f = 0; f < 4; ++f) {
            int bo = (f * 16 + lrow) * 64 + lk8 * 2;
            bf16x8 bqh = *(const bf16x8*)(wlds[buf] + bo);
            bf16x8 bql = *(const bf16x8*)(wlds[buf] + 4096 + bo);
            bf16x8 bkh = *(const bf16x8*)(wlds[buf] + 8192 + bo);
            bf16x8 bkl = *(const bf16x8*)(wlds[buf] + 12288 + bo);
#pragma unroll
            for (int rt = 0; rt < 2; ++rt) {
                accq[rt][f] = MFMA16(ah[rt], bqh, accq[rt][f]);
                accq[rt][f] = MFMA16(ah[rt], bql, accq[rt][f]);
                accq[rt][f] = MFMA16(al[rt], bqh, accq[rt][f]);
                acck[rt][f] = MFMA16(ah[rt], bkh, acck[rt][f]);
                acck[rt][f] = MFMA16(ah[rt], bkl, acck[rt][f]);
                acck[rt][f] = MFMA16(al[rt], bkh, acck[rt][f]);
            }
        }
        block_sync();
        if (ks < 23) {
#pragma unroll
            for (int rt = 0; rt < 2; ++rt) {
                ah[rt] = ahn[rt];
                al[rt] = aln[rt];
            }
        }
        buf ^= 1;
    }

    char* khb = (char*)kh_o + (size_t)head * SEQ * DK * 2;
    char* klb = (char*)kl_o + (size_t)head * SEQ * DK * 2;
#pragma unroll
    for (int rt = 0; rt < 2; ++rt)
#pragma unroll
        for (int f = 0; f < 4; ++f)
#pragma unroll
            for (int r = 0; r < 4; ++r) {
                int srow_o = rowbase + rt * 16 + g4 + r;  // key / seq row
                int d = f * 16 + lrow;
                // Q: row-major
                size_t o = (size_t)head * SEQ * DK + (size_t)srow_o * DK + d;
                float qv = accq[rt][f][r];
                __bf16 qhh = (__bf16)qv;
                qh_o[o] = qhh;
                ql_o[o] = (__bf16)(qv - (float)qhh);
                // K: fragment-linear
                size_t ko = (size_t)(srow_o >> 6) * 8192 + ((srow_o >> 5) & 1) * 4096
                          + (size_t)f * 1024
                          + ((srow_o & 31) + 32 * ((lrow >> 3) & 1)) * 16 + (lrow & 7) * 2;
                float kv = acck[rt][f][r];
                __bf16 khh = (__bf16)kv;
                *(__bf16*)(khb + ko) = khh;
                *(__bf16*)(klb + ko) = (__bf16)(kv - (float)khh);
            }
}

// ---------------------------------------------------------------------------
// Kernel 2b: V projection (1-term, operand-swapped). V written in
// FRAGMENT-LINEAR layout (PV B-frag order).
// ---------------------------------------------------------------------------
__global__ __launch_bounds__(256) void proj_v_kernel(
    const __bf16* __restrict__ xh, const __bf16* __restrict__ w_v,
    __bf16* __restrict__ vt_o) {
    __shared__ char wlds[2][4096];

    const int wg = (blockIdx.x & 7) * 48 + (blockIdx.x >> 3);
    const int head = wg >> 5;
    const int rb = wg & 31;
    const int wave = threadIdx.x >> 6;
    const int lane = threadIdx.x & 63;
    const int lrow = lane & 15;
    const int lk8 = (lane >> 4) * 8;
    const int g4 = (lane >> 4) * 4;
    const int rowbase = rb * 128 + wave * 32;

    const char* wv_b = (const char*)(w_v + head * DK * E);
    const int srow = lane >> 2;
    const int scol = (lane & 3) * 16;

    auto STAGE = [&](int buf, int ks) {
        const char* src = wv_b + (size_t)(wave * 16 + srow) * (E * 2) + ks * 64 + scol;
        gload16(src, wlds[buf] + wave * 1024 + lane * 16);
    };

    f32x4 acc[2][4];
#pragma unroll
    for (int rt = 0; rt < 2; ++rt)
#pragma unroll
        for (int f = 0; f < 4; ++f) acc[rt][f] = (f32x4){0.f, 0.f, 0.f, 0.f};

    bf16x8 ah[2], ahn[2];
    auto LOADA = [&](int ks, bf16x8* h) {
#pragma unroll
        for (int rt = 0; rt < 2; ++rt) {
            size_t xo = (size_t)(rowbase + rt * 16 + lrow) * E + ks * 32 + lk8;
            h[rt] = *(const bf16x8*)(xh + xo);
        }
    };

    LOADA(0, ah);
    STAGE(0, 0);
    int buf = 0;
    for (int ks = 0; ks < 24; ++ks) {
        if (ks < 23) {
            LOADA(ks + 1, ahn);
            STAGE(buf ^ 1, ks + 1);
            asm volatile("s_waitcnt vmcnt(3)" ::: "memory");
        } else {
            asm volatile("s_waitcnt vmcnt(0)" ::: "memory");
        }
        block_sync();
#pragma unroll
        for (int f = 0; f < 4; ++f) {
            int bo = (f * 16 + lrow) * 64 + lk8 * 2;
            bf16x8 bv = *(const bf16x8*)(wlds[buf] + bo);
#pragma unroll
            for (int rt = 0; rt < 2; ++rt)
                acc[rt][f] = MFMA16(bv, ah[rt], acc[rt][f]);  // D[d][s]
        }
        block_sync();
        if (ks < 23) {
#pragma unroll
            for (int rt = 0; rt < 2; ++rt) ah[rt] = ahn[rt];
        }
        buf ^= 1;
    }

    char* vb = (char*)vt_o + (size_t)head * DK * SEQ * 2;
#pragma unroll
    for (int rt = 0; rt < 2; ++rt)
#pragma unroll
        for (int f = 0; f < 4; ++f)
#pragma unroll
            for (int r = 0; r < 4; ++r) {
                int vd = f * 16 + g4 + r;              // d
                int vs = rowbase + rt * 16 + lrow;     // key
                size_t vo = (size_t)(vs >> 6) * 8192 + ((vd >> 5) & 1) * 4096
                          + ((vs >> 4) & 3) * 1024
                          + ((vd & 31) + 32 * ((vs >> 3) & 1)) * 16 + (vs & 7) * 2;
                *(__bf16*)(vb + vo) = (__bf16)acc[rt][f][r];
            }
}

// ---------------------------------------------------------------------------
// Kernel 3: causal flash attention — split-KV x4, barrier-free main loop.
// Block = 256 thr = 4 independent waves on ONE 32-row q-window; wave i does
// tiles i, i+4, ... K(hi,lo)/V read from global in FRAGMENT-LINEAR layout:
// every load is base + lane*16 — a single coalesced 1KB burst (16 lines)
// instead of r10's 32-line gather (2x line-requests; request-rate bound).
// Swapped 32x32x16 MFMA, in-register softmax/P, defer-max, LDS flash-merge.
// ---------------------------------------------------------------------------
__global__ __launch_bounds__(256, 2) void attn_kernel(
    const __bf16* __restrict__ qh, const __bf16* __restrict__ ql,
    const __bf16* __restrict__ kh, const __bf16* __restrict__ kl,
    const __bf16* __restrict__ vt,
    float* __restrict__ out) {
    __shared__ float cbuf[3][64][33];  // waves 1..3 rescaled O partials (bank-safe)
    __shared__ float mlb[4][2][32];    // [wave][0=m,1=l'][row]

    const int wg = (blockIdx.x & 7) * 192 + (blockIdx.x >> 3);  // 1536 = 8 x 192
    const int head = wg >> 7;               // 0..11
    const int window = 127 - (wg & 127);    // heavy-first
    const int rowbase = window * 32;
    const int wave = threadIdx.x >> 6;
    const int lane = threadIdx.x & 63;
    const int lq = lane & 31;
    const int lh = lane >> 5;

    const size_t hoff = (size_t)head * SEQ * DK;

    // Q B-frags: lane holds Q[rowbase+lq][ds*16 + lh*8 + 0..7]
    bf16x8 qBh[4], qBl[4];
    {
        const __bf16* qph = qh + hoff + (size_t)(rowbase + lq) * DK + lh * 8;
        const __bf16* qpl = ql + hoff + (size_t)(rowbase + lq) * DK + lh * 8;
#pragma unroll
        for (int ds = 0; ds < 4; ++ds) {
            qBh[ds] = *(const bf16x8*)(qph + ds * 16);
            qBl[ds] = *(const bf16x8*)(qpl + ds * 16);
        }
    }

    // fragment-linear walking pointers (each load: +lane*16, 1KB coalesced)
    const char* kh_p = (const char*)(kh + hoff) + wave * 8192 + lane * 16;
    const char* kl_p = (const char*)(kl + hoff) + wave * 8192 + lane * 16;
    const char* vt_p = (const char*)(vt + (size_t)head * DK * SEQ) + wave * 8192 + lane * 16;

    f32x16 O0 = (f32x16)0.0f, O1 = (f32x16)0.0f;
    float m = -3.0e38f, lsum = 0.f;

    const int nt = (window >> 1) + 1;

    for (int t = wave; t < nt; t += 4) {
        const int kb = t * 64;

        // ---- S = K'^T Q (log2 units). s0: keys kb..kb+31, s1: +32..63 ----
        f32x16 s0 = (f32x16)0.0f, s1 = (f32x16)0.0f;
#pragma unroll
        for (int ds = 0; ds < 4; ++ds) {
            bf16x8 ah0 = *(const bf16x8*)(kh_p + ds * 1024);
            bf16x8 al0 = *(const bf16x8*)(kl_p + ds * 1024);
            bf16x8 ah1 = *(const bf16x8*)(kh_p + 4096 + ds * 1024);
            bf16x8 al1 = *(const bf16x8*)(kl_p + 4096 + ds * 1024);
            s0 = MFMA32(ah0, qBh[ds], s0);
            s1 = MFMA32(ah1, qBh[ds], s1);
            s0 = MFMA32(al0, qBh[ds], s0);
            s1 = MFMA32(al1, qBh[ds], s1);
            s0 = MFMA32(ah0, qBl[ds], s0);
            s1 = MFMA32(ah1, qBl[ds], s1);
        }

        // ---- causal mask (only the diagonal tile triggers) ----
        if (kb + 63 > rowbase) {
            int qa = rowbase + lq;
#pragma unroll
            for (int r = 0; r < 16; ++r) {
                int kp = kb + ((r & 3) + 8 * (r >> 2) + 4 * lh);
                if (kp > qa) s0[r] = -1.0e30f;
                if (kp + 32 > qa) s1[r] = -1.0e30f;
            }
        }

        // ---- row max: 4-chain tree + one cross-half swap ----
        float x0 = fmaxf(s0[0], s0[1]), x1 = fmaxf(s0[2], s0[3]);
        float x2 = fmaxf(s0[4], s0[5]), x3 = fmaxf(s0[6], s0[7]);
#pragma unroll
        for (int r = 8; r < 16; r += 4) {
            x0 = fmaxf(x0, fmaxf(s0[r], s0[r + 1]));
            x1 = fmaxf(x1, fmaxf(s0[r + 2], s0[r + 3]));
        }
#pragma unroll
        for (int r = 0; r < 16; r += 4) {
            x2 = fmaxf(x2, fmaxf(s1[r], s1[r + 1]));
            x3 = fmaxf(x3, fmaxf(s1[r + 2], s1[r + 3]));
        }
        float mx = xhalf_max(fmaxf(fmaxf(x0, x1), fmaxf(x2, x3)));

        // ---- defer-max rescale (rare); alpha broadcast via shfl ----
        if (!__all(mx - m <= DEFER)) {
            float mn = fmaxf(m, mx);
            float al = exp2f(m - mn);
            m = mn;
            lsum *= al;
#pragma unroll
            for (int r = 0; r < 16; ++r) {
                float a = __shfl(al, (r & 3) + 8 * (r >> 2) + 4 * lh);
                O0[r] *= a;
                O1[r] *= a;
            }
        }

        // ---- P = exp2(S - m); l accumulation ----
#pragma unroll
        for (int r = 0; r < 16; ++r) {
            s0[r] = exp2f(s0[r] - m);
            s1[r] = exp2f(s1[r] - m);
        }
        {
            float p0 = 0.f, p1 = 0.f, p2 = 0.f, p3 = 0.f;
#pragma unroll
            for (int r = 0; r < 16; r += 4) {
                p0 += s0[r] + s0[r + 1];
                p1 += s0[r + 2] + s0[r + 3];
                p2 += s1[r] + s1[r + 1];
                p3 += s1[r + 2] + s1[r + 3];
            }
            lsum += (p0 + p1) + (p2 + p3);
        }

        // ---- P -> PV A-frags: cvt_pk + permlane32_swap (in-register) ----
        unsigned W0 = cvtpk(s0[0], s0[1]), W1 = cvtpk(s0[2], s0[3]);
        unsigned W2 = cvtpk(s0[4], s0[5]), W3 = cvtpk(s0[6], s0[7]);
        unsigned W4 = cvtpk(s0[8], s0[9]), W5 = cvtpk(s0[10], s0[11]);
        unsigned W6 = cvtpk(s0[12], s0[13]), W7 = cvtpk(s0[14], s0[15]);
        u32x2 rA = plswap(W0, W2), rB = plswap(W1, W3);
        u32x2 rC = plswap(W4, W6), rD = plswap(W5, W7);
        bf16x8 p00 = __builtin_bit_cast(bf16x8, (u32x4){rA.x, rB.x, rA.y, rB.y});
        bf16x8 p01 = __builtin_bit_cast(bf16x8, (u32x4){rC.x, rD.x, rC.y, rD.y});
        W0 = cvtpk(s1[0], s1[1]); W1 = cvtpk(s1[2], s1[3]);
        W2 = cvtpk(s1[4], s1[5]); W3 = cvtpk(s1[6], s1[7]);
        W4 = cvtpk(s1[8], s1[9]); W5 = cvtpk(s1[10], s1[11]);
        W6 = cvtpk(s1[12], s1[13]); W7 = cvtpk(s1[14], s1[15]);
        rA = plswap(W0, W2); rB = plswap(W1, W3);
        rC = plswap(W4, W6); rD = plswap(W5, W7);
        bf16x8 p10 = __builtin_bit_cast(bf16x8, (u32x4){rA.x, rB.x, rA.y, rB.y});
        bf16x8 p11 = __builtin_bit_cast(bf16x8, (u32x4){rC.x, rD.x, rC.y, rD.y});

        // ---- O += P V (B-frags: fragment-linear, 1KB coalesced) ----
        {
            bf16x8 v00 = *(const bf16x8*)(vt_p + 0);
            bf16x8 v01 = *(const bf16x8*)(vt_p + 1024);
            bf16x8 v10 = *(const bf16x8*)(vt_p + 2048);
            bf16x8 v11 = *(const bf16x8*)(vt_p + 3072);
            O0 = MFMA32(p00, v00, O0);
            O0 = MFMA32(p01, v01, O0);
            O0 = MFMA32(p10, v10, O0);
            O0 = MFMA32(p11, v11, O0);
            bf16x8 w00 = *(const bf16x8*)(vt_p + 4096);
            bf16x8 w01 = *(const bf16x8*)(vt_p + 5120);
            bf16x8 w10 = *(const bf16x8*)(vt_p + 6144);
            bf16x8 w11 = *(const bf16x8*)(vt_p + 7168);
            O1 = MFMA32(p00, w00, O1);
            O1 = MFMA32(p01, w01, O1);
            O1 = MFMA32(p10, w10, O1);
            O1 = MFMA32(p11, w11, O1);
        }

        kh_p += 4 * 8192;   // next owned tile (stride 4)
        kl_p += 4 * 8192;
        vt_p += 4 * 8192;
    }

    // ---- combine the 4 split-KV partials (flash merge in LDS) ----
    if (lh == 0) mlb[wave][0][lq] = m;
    __syncthreads();
    float mstar = fmaxf(fmaxf(mlb[0][0][lq], mlb[1][0][lq]),
                        fmaxf(mlb[2][0][lq], mlb[3][0][lq]));
    float sc = exp2f(m - mstar);
    float lp = xhalf_add(lsum) * sc;
#pragma unroll
    for (int r = 0; r < 16; ++r) {
        float a = __shfl(sc, (r & 3) + 8 * (r >> 2) + 4 * lh);
        O0[r] *= a;
        O1[r] *= a;
    }
    if (wave > 0) {
        if (lh == 0) mlb[wave][1][lq] = lp;
        float* cb = &cbuf[wave - 1][lane][0];
#pragma unroll
        for (int r = 0; r < 16; ++r) {
            cb[r] = O0[r];
            cb[16 + r] = O1[r];
        }
    }
    __syncthreads();
    if (wave == 0) {
        float ltot = lp + mlb[1][1][lq] + mlb[2][1][lq] + mlb[3][1][lq];
#pragma unroll
        for (int i = 0; i < 3; ++i) {
            const float* cb = &cbuf[i][lane][0];
#pragma unroll
            for (int r = 0; r < 16; ++r) {
                O0[r] += cb[r];
                O1[r] += cb[16 + r];
            }
        }
        float linv = 1.0f / ltot;
#pragma unroll
        for (int r = 0; r < 16; ++r) {
            int rr = (r & 3) + 8 * (r >> 2) + 4 * lh;
            float li = __shfl(linv, rr);
            size_t o = hoff + (size_t)(rowbase + rr) * DK + lq;
            out[o] = O0[r] * li;
            out[o + 32] = O1[r] * li;
        }
    }
}

// ---------------------------------------------------------------------------
extern "C" void kernel_launch(void* const* d_in, const int* in_sizes, int n_in,
                              void* d_out, int out_size, void* d_ws, size_t ws_size,
                              hipStream_t stream) {
    const float* x = (const float*)d_in[0];
    const float* qp = (const float*)d_in[1];
    const float* kp = (const float*)d_in[2];
    const float* vp = (const float*)d_in[3];
    float* out = (float*)d_out;

    const size_t WT_SZ = (size_t)NH * DK * E * 2;     // 1,179,648 B
    const size_t QKV_SZ = (size_t)NH * SEQ * DK * 2;  // 6,291,456 B
    const size_t X_SZ = (size_t)SEQ * E * 2;          // 6,291,456 B
    char* ws = (char*)d_ws;
    __bf16* wtq_h = (__bf16*)(ws + 0 * WT_SZ);
    __bf16* wtq_l = (__bf16*)(ws + 1 * WT_SZ);
    __bf16* wtk_h = (__bf16*)(ws + 2 * WT_SZ);
    __bf16* wtk_l = (__bf16*)(ws + 3 * WT_SZ);
    __bf16* wtv_h = (__bf16*)(ws + 4 * WT_SZ);
    char* p2 = ws + 5 * WT_SZ;
    __bf16* qh = (__bf16*)(p2 + 0 * QKV_SZ);
    __bf16* ql = (__bf16*)(p2 + 1 * QKV_SZ);
    __bf16* kh = (__bf16*)(p2 + 2 * QKV_SZ);
    __bf16* kl = (__bf16*)(p2 + 3 * QKV_SZ);
    __bf16* vt = (__bf16*)(p2 + 4 * QKV_SZ);
    char* p3 = p2 + 5 * QKV_SZ;
    __bf16* xh = (__bf16*)(p3 + 0 * X_SZ);
    __bf16* xl = (__bf16*)(p3 + 1 * X_SZ);

    hipLaunchKernelGGL(xsplit_kernel, dim3(SEQ * E / 4 / 256), dim3(256), 0, stream,
                       x, xh, xl);
    hipLaunchKernelGGL(wsplit_kernel, dim3((NH * E * DK + 255) / 256), dim3(256), 0, stream,
                       qp, kp, vp, wtq_h, wtq_l, wtk_h, wtk_l, wtv_h);
    hipLaunchKernelGGL(proj_qk_kernel, dim3(384), dim3(256), 0, stream,
                       xh, xl, wtq_h, wtq_l, wtk_h, wtk_l, qh, ql, kh, kl);
    hipLaunchKernelGGL(proj_v_kernel, dim3(384), dim3(256), 0, stream,
                       xh, wtv_h, vt);
    hipLaunchKernelGGL(attn_kernel, dim3(1536), dim3(256), 0, stream,
                       qh, ql, kh, kl, vt, out);
}

// Round 12
// 176.891 us; speedup vs baseline: 1.5847x; 1.0289x over previous
//
#include <hip/hip_runtime.h>
#include <hip/hip_bf16.h>

#define NH 12
#define SEQ 4096
#define E 768
#define DK 64

typedef float f32x4 __attribute__((ext_vector_type(4)));
typedef float f32x16 __attribute__((ext_vector_type(16)));
typedef __bf16 bf16x8 __attribute__((ext_vector_type(8)));
typedef __bf16 bf16x4 __attribute__((ext_vector_type(4)));
typedef unsigned u32x2 __attribute__((ext_vector_type(2)));
typedef unsigned u32x4 __attribute__((ext_vector_type(4)));

#define MFMA16(a, b, c) __builtin_amdgcn_mfma_f32_16x16x32_bf16((a), (b), (c), 0, 0, 0)
#define MFMA32(a, b, c) __builtin_amdgcn_mfma_f32_32x32x16_bf16((a), (b), (c), 0, 0, 0)

// log2(e) / sqrt(dk); folded into K weights at wsplit time.
#define SCL 0.18033688011112042f
// defer-max threshold in log2 units: P bounded by 2^10.8
#define DEFER 10.8f

__device__ __forceinline__ void gload16(const void* g, void* l) {
    __builtin_amdgcn_global_load_lds(
        (const __attribute__((address_space(1))) void*)g,
        (__attribute__((address_space(3))) void*)l, 16, 0, 0);
}

__device__ __forceinline__ void block_sync() {
    __builtin_amdgcn_sched_barrier(0);
    __builtin_amdgcn_s_barrier();
    __builtin_amdgcn_sched_barrier(0);
}

__device__ __forceinline__ unsigned cvtpk(float lo, float hi) {
    unsigned r;
    asm("v_cvt_pk_bf16_f32 %0, %1, %2" : "=v"(r) : "v"(lo), "v"(hi));
    return r;
}
__device__ __forceinline__ u32x2 plswap(unsigned a, unsigned b) {
    return __builtin_amdgcn_permlane32_swap(a, b, false, false);
}
__device__ __forceinline__ float xhalf_max(float v) {
    u32x2 r = plswap(__float_as_uint(v), __float_as_uint(v));
    return fmaxf(__uint_as_float(r.x), __uint_as_float(r.y));
}
__device__ __forceinline__ float xhalf_add(float v) {
    u32x2 r = plswap(__float_as_uint(v), __float_as_uint(v));
    return __uint_as_float(r.x) + __uint_as_float(r.y);
}

// ---------------------------------------------------------------------------
// Kernel 0: split x into bf16 hi/lo
// ---------------------------------------------------------------------------
__global__ __launch_bounds__(256) void xsplit_kernel(const float* __restrict__ x,
                                                     __bf16* __restrict__ xh,
                                                     __bf16* __restrict__ xl) {
    int i = blockIdx.x * blockDim.x + threadIdx.x;
    float4 v = ((const float4*)x)[i];
    bf16x4 h, l;
    float vv[4] = {v.x, v.y, v.z, v.w};
#pragma unroll
    for (int j = 0; j < 4; ++j) {
        __bf16 hh = (__bf16)vv[j];
        h[j] = hh;
        l[j] = (__bf16)(vv[j] - (float)hh);
    }
    ((bf16x4*)xh)[i] = h;
    ((bf16x4*)xl)[i] = l;
}

// ---------------------------------------------------------------------------
// Kernel 1: split projection weights (hi/lo), transpose to [h][n][k].
// K weights pre-scaled by SCL so attention scores come out in log2 units.
// ---------------------------------------------------------------------------
__global__ void wsplit_kernel(const float* __restrict__ qp,
                              const float* __restrict__ kp,
                              const float* __restrict__ vp,
                              __bf16* __restrict__ wtq_h, __bf16* __restrict__ wtq_l,
                              __bf16* __restrict__ wtk_h, __bf16* __restrict__ wtk_l,
                              __bf16* __restrict__ wtv_h) {
    int idx = blockIdx.x * blockDim.x + threadIdx.x;
    if (idx >= NH * E * DK) return;
    int h = idx / (E * DK);
    int rem = idx - h * E * DK;
    int k = rem / DK;
    int n = rem - k * DK;
    int o = h * DK * E + n * E + k;  // [h][n][k]
    float q = qp[idx];
    __bf16 qh = (__bf16)q;
    wtq_h[o] = qh;
    wtq_l[o] = (__bf16)(q - (float)qh);
    float kk = kp[idx] * SCL;
    __bf16 kh = (__bf16)kk;
    wtk_h[o] = kh;
    wtk_l[o] = (__bf16)(kk - (float)kh);
    wtv_h[o] = (__bf16)vp[idx];
}

// ---------------------------------------------------------------------------
// Kernel 2a: fused Q+K projection. Block = 64 rows x 1 head, 4 waves x 16
// rows. Grid 768 = exactly 3 blocks/CU (balanced; r11's 384 = 1.5/CU was
// imbalanced). Wq/Wk hi+lo staged in LDS (dbuf, counted vmcnt).
// Q written row-major; K written FRAGMENT-LINEAR.
// ---------------------------------------------------------------------------
__global__ __launch_bounds__(256, 2) void proj_qk_kernel(
    const __bf16* __restrict__ xh, const __bf16* __restrict__ xl,
    const __bf16* __restrict__ wq_h_g, const __bf16* __restrict__ wq_l_g,
    const __bf16* __restrict__ wk_h_g, const __bf16* __restrict__ wk_l_g,
    __bf16* __restrict__ qh_o, __bf16* __restrict__ ql_o,
    __bf16* __restrict__ kh_o, __bf16* __restrict__ kl_o) {
    __shared__ char wlds[2][16384];  // [buf][ Wqh 4K | Wql 4K | Wkh 4K | Wkl 4K ]

    const int wg = (blockIdx.x & 7) * 96 + (blockIdx.x >> 3);  // 768 = 8 x 96
    const int head = wg >> 6;  // /64
    const int rb = wg & 63;    // 0..63 (64-row block)
    const int wave = threadIdx.x >> 6;
    const int lane = threadIdx.x & 63;
    const int lrow = lane & 15;
    const int lk8 = (lane >> 4) * 8;
    const int g4 = (lane >> 4) * 4;
    const int rowbase = rb * 64 + wave * 16;

    const char* wq_h_b = (const char*)(wq_h_g + head * DK * E);
    const char* wq_l_b = (const char*)(wq_l_g + head * DK * E);
    const char* wk_h_b = (const char*)(wk_h_g + head * DK * E);
    const char* wk_l_b = (const char*)(wk_l_g + head * DK * E);
    const char* base = (wave == 0) ? wq_h_b : (wave == 1) ? wq_l_b
                      : (wave == 2) ? wk_h_b : wk_l_b;
    const int srow = lane >> 2;        // 0..15
    const int scol = (lane & 3) * 16;  // byte in 64B row-slice

    auto STAGE = [&](int buf, int ks) {
#pragma unroll
        for (int r = 0; r < 4; ++r) {
            const char* src = base + (size_t)(r * 16 + srow) * (E * 2) + ks * 64 + scol;
            gload16(src, wlds[buf] + (wave * 4 + r) * 1024 + lane * 16);
        }
    };

    f32x4 accq[4], acck[4];
#pragma unroll
    for (int f = 0; f < 4; ++f) {
        accq[f] = (f32x4){0.f, 0.f, 0.f, 0.f};
        acck[f] = (f32x4){0.f, 0.f, 0.f, 0.f};
    }

    bf16x8 ah, al, ahn, aln;
    auto LOADA = [&](int ks, bf16x8& h, bf16x8& l) {
        size_t xo = (size_t)(rowbase + lrow) * E + ks * 32 + lk8;
        h = *(const bf16x8*)(xh + xo);
        l = *(const bf16x8*)(xl + xo);
    };

    LOADA(0, ah, al);
    STAGE(0, 0);
    int buf = 0;
    for (int ks = 0; ks < 24; ++ks) {
        if (ks < 23) {
            LOADA(ks + 1, ahn, aln);
            STAGE(buf ^ 1, ks + 1);
            asm volatile("s_waitcnt vmcnt(6)" ::: "memory");
        } else {
            asm volatile("s_waitcnt vmcnt(0)" ::: "memory");
        }
        block_sync();
#pragma unroll
        for (int f = 0; f < 4; ++f) {
            int bo = (f * 16 + lrow) * 64 + lk8 * 2;
            bf16x8 bqh = *(const bf16x8*)(wlds[buf] + bo);
            bf16x8 bql = *(const bf16x8*)(wlds[buf] + 4096 + bo);
            bf16x8 bkh = *(const bf16x8*)(wlds[buf] + 8192 + bo);
            bf16x8 bkl = *(const bf16x8*)(wlds[buf] + 12288 + bo);
            accq[f] = MFMA16(ah, bqh, accq[f]);
            accq[f] = MFMA16(ah, bql, accq[f]);
            accq[f] = MFMA16(al, bqh, accq[f]);
            acck[f] = MFMA16(ah, bkh, acck[f]);
            acck[f] = MFMA16(ah, bkl, acck[f]);
            acck[f] = MFMA16(al, bkh, acck[f]);
        }
        block_sync();
        if (ks < 23) {
            ah = ahn;
            al = aln;
        }
        buf ^= 1;
    }

    char* khb = (char*)kh_o + (size_t)head * SEQ * DK * 2;
    char* klb = (char*)kl_o + (size_t)head * SEQ * DK * 2;
#pragma unroll
    for (int f = 0; f < 4; ++f)
#pragma unroll
        for (int r = 0; r < 4; ++r) {
            int srow_o = rowbase + g4 + r;  // key / seq row
            int d = f * 16 + lrow;
            // Q: row-major
            size_t o = (size_t)head * SEQ * DK + (size_t)srow_o * DK + d;
            float qv = accq[f][r];
            __bf16 qhh = (__bf16)qv;
            qh_o[o] = qhh;
            ql_o[o] = (__bf16)(qv - (float)qhh);
            // K: fragment-linear
            size_t ko = (size_t)(srow_o >> 6) * 8192 + ((srow_o >> 5) & 1) * 4096
                      + (size_t)f * 1024
                      + ((srow_o & 31) + 32 * ((lrow >> 3) & 1)) * 16 + (lrow & 7) * 2;
            float kv = acck[f][r];
            __bf16 khh = (__bf16)kv;
            *(__bf16*)(khb + ko) = khh;
            *(__bf16*)(klb + ko) = (__bf16)(kv - (float)khh);
        }
}

// ---------------------------------------------------------------------------
// Kernel 2b: V projection (1-term, operand-swapped). Block = 64 rows, 4
// waves x 16 rows, grid 768 (3 blocks/CU balanced). V written FRAGMENT-LINEAR.
// ---------------------------------------------------------------------------
__global__ __launch_bounds__(256) void proj_v_kernel(
    const __bf16* __restrict__ xh, const __bf16* __restrict__ w_v,
    __bf16* __restrict__ vt_o) {
    __shared__ char wlds[2][4096];

    const int wg = (blockIdx.x & 7) * 96 + (blockIdx.x >> 3);  // 768 = 8 x 96
    const int head = wg >> 6;
    const int rb = wg & 63;
    const int wave = threadIdx.x >> 6;
    const int lane = threadIdx.x & 63;
    const int lrow = lane & 15;
    const int lk8 = (lane >> 4) * 8;
    const int g4 = (lane >> 4) * 4;
    const int rowbase = rb * 64 + wave * 16;

    const char* wv_b = (const char*)(w_v + head * DK * E);
    const int srow = lane >> 2;
    const int scol = (lane & 3) * 16;

    auto STAGE = [&](int buf, int ks) {
        const char* src = wv_b + (size_t)(wave * 16 + srow) * (E * 2) + ks * 64 + scol;
        gload16(src, wlds[buf] + wave * 1024 + lane * 16);
    };

    f32x4 acc[4];
#pragma unroll
    for (int f = 0; f < 4; ++f) acc[f] = (f32x4){0.f, 0.f, 0.f, 0.f};

    bf16x8 ah, ahn;
    auto LOADA = [&](int ks, bf16x8& h) {
        size_t xo = (size_t)(rowbase + lrow) * E + ks * 32 + lk8;
        h = *(const bf16x8*)(xh + xo);
    };

    LOADA(0, ah);
    STAGE(0, 0);
    int buf = 0;
    for (int ks = 0; ks < 24; ++ks) {
        if (ks < 23) {
            LOADA(ks + 1, ahn);
            STAGE(buf ^ 1, ks + 1);
            asm volatile("s_waitcnt vmcnt(2)" ::: "memory");
        } else {
            asm volatile("s_waitcnt vmcnt(0)" ::: "memory");
        }
        block_sync();
#pragma unroll
        for (int f = 0; f < 4; ++f) {
            int bo = (f * 16 + lrow) * 64 + lk8 * 2;
            bf16x8 bv = *(const bf16x8*)(wlds[buf] + bo);
            acc[f] = MFMA16(bv, ah, acc[f]);  // D[d][s]
        }
        block_sync();
        if (ks < 23) ah = ahn;
        buf ^= 1;
    }

    char* vb = (char*)vt_o + (size_t)head * DK * SEQ * 2;
#pragma unroll
    for (int f = 0; f < 4; ++f)
#pragma unroll
        for (int r = 0; r < 4; ++r) {
            int vd = f * 16 + g4 + r;          // d
            int vs = rowbase + lrow;           // key
            size_t vo = (size_t)(vs >> 6) * 8192 + ((vd >> 5) & 1) * 4096
                      + ((vs >> 4) & 3) * 1024
                      + ((vd & 31) + 32 * ((vs >> 3) & 1)) * 16 + (vs & 7) * 2;
            *(__bf16*)(vb + vo) = (__bf16)acc[f][r];
        }
}

// ---------------------------------------------------------------------------
// Kernel 3: causal flash attention — split-KV x4, barrier-free main loop.
// Fragment-linear K/V (1KB coalesced bursts). V loads hoisted ABOVE the
// softmax so their L2 latency hides under the exp/max chain. Swapped
// 32x32x16 MFMA, in-register softmax/P, defer-max, LDS flash-merge.
// ---------------------------------------------------------------------------
__global__ __launch_bounds__(256, 2) void attn_kernel(
    const __bf16* __restrict__ qh, const __bf16* __restrict__ ql,
    const __bf16* __restrict__ kh, const __bf16* __restrict__ kl,
    const __bf16* __restrict__ vt,
    float* __restrict__ out) {
    __shared__ float cbuf[3][64][33];  // waves 1..3 rescaled O partials (bank-safe)
    __shared__ float mlb[4][2][32];    // [wave][0=m,1=l'][row]

    const int wg = (blockIdx.x & 7) * 192 + (blockIdx.x >> 3);  // 1536 = 8 x 192
    const int head = wg >> 7;               // 0..11
    const int window = 127 - (wg & 127);    // heavy-first
    const int rowbase = window * 32;
    const int wave = threadIdx.x >> 6;
    const int lane = threadIdx.x & 63;
    const int lq = lane & 31;
    const int lh = lane >> 5;

    const size_t hoff = (size_t)head * SEQ * DK;

    // Q B-frags: lane holds Q[rowbase+lq][ds*16 + lh*8 + 0..7]
    bf16x8 qBh[4], qBl[4];
    {
        const __bf16* qph = qh + hoff + (size_t)(rowbase + lq) * DK + lh * 8;
        const __bf16* qpl = ql + hoff + (size_t)(rowbase + lq) * DK + lh * 8;
#pragma unroll
        for (int ds = 0; ds < 4; ++ds) {
            qBh[ds] = *(const bf16x8*)(qph + ds * 16);
            qBl[ds] = *(const bf16x8*)(qpl + ds * 16);
        }
    }

    // fragment-linear walking pointers (each load: +lane*16, 1KB coalesced)
    const char* kh_p = (const char*)(kh + hoff) + wave * 8192 + lane * 16;
    const char* kl_p = (const char*)(kl + hoff) + wave * 8192 + lane * 16;
    const char* vt_p = (const char*)(vt + (size_t)head * DK * SEQ) + wave * 8192 + lane * 16;

    f32x16 O0 = (f32x16)0.0f, O1 = (f32x16)0.0f;
    float m = -3.0e38f, lsum = 0.f;

    const int nt = (window >> 1) + 1;

    for (int t = wave; t < nt; t += 4) {
        const int kb = t * 64;

        // ---- S = K'^T Q (log2 units). s0: keys kb..kb+31, s1: +32..63 ----
        f32x16 s0 = (f32x16)0.0f, s1 = (f32x16)0.0f;
#pragma unroll
        for (int ds = 0; ds < 4; ++ds) {
            bf16x8 ah0 = *(const bf16x8*)(kh_p + ds * 1024);
            bf16x8 al0 = *(const bf16x8*)(kl_p + ds * 1024);
            bf16x8 ah1 = *(const bf16x8*)(kh_p + 4096 + ds * 1024);
            bf16x8 al1 = *(const bf16x8*)(kl_p + 4096 + ds * 1024);
            s0 = MFMA32(ah0, qBh[ds], s0);
            s1 = MFMA32(ah1, qBh[ds], s1);
            s0 = MFMA32(al0, qBh[ds], s0);
            s1 = MFMA32(al1, qBh[ds], s1);
            s0 = MFMA32(ah0, qBl[ds], s0);
            s1 = MFMA32(ah1, qBl[ds], s1);
        }

        // ---- V B-frags issued EARLY: latency hides under the softmax ----
        bf16x8 v00 = *(const bf16x8*)(vt_p + 0);
        bf16x8 v01 = *(const bf16x8*)(vt_p + 1024);
        bf16x8 v10 = *(const bf16x8*)(vt_p + 2048);
        bf16x8 v11 = *(const bf16x8*)(vt_p + 3072);
        bf16x8 w00 = *(const bf16x8*)(vt_p + 4096);
        bf16x8 w01 = *(const bf16x8*)(vt_p + 5120);
        bf16x8 w10 = *(const bf16x8*)(vt_p + 6144);
        bf16x8 w11 = *(const bf16x8*)(vt_p + 7168);

        // ---- causal mask (only the diagonal tile triggers) ----
        if (kb + 63 > rowbase) {
            int qa = rowbase + lq;
#pragma unroll
            for (int r = 0; r < 16; ++r) {
                int kp = kb + ((r & 3) + 8 * (r >> 2) + 4 * lh);
                if (kp > qa) s0[r] = -1.0e30f;
                if (kp + 32 > qa) s1[r] = -1.0e30f;
            }
        }

        // ---- row max: 4-chain tree + one cross-half swap ----
        float x0 = fmaxf(s0[0], s0[1]), x1 = fmaxf(s0[2], s0[3]);
        float x2 = fmaxf(s0[4], s0[5]), x3 = fmaxf(s0[6], s0[7]);
#pragma unroll
        for (int r = 8; r < 16; r += 4) {
            x0 = fmaxf(x0, fmaxf(s0[r], s0[r + 1]));
            x1 = fmaxf(x1, fmaxf(s0[r + 2], s0[r + 3]));
        }
#pragma unroll
        for (int r = 0; r < 16; r += 4) {
            x2 = fmaxf(x2, fmaxf(s1[r], s1[r + 1]));
            x3 = fmaxf(x3, fmaxf(s1[r + 2], s1[r + 3]));
        }
        float mx = xhalf_max(fmaxf(fmaxf(x0, x1), fmaxf(x2, x3)));

        // ---- defer-max rescale (rare); alpha broadcast via shfl ----
        if (!__all(mx - m <= DEFER)) {
            float mn = fmaxf(m, mx);
            float al = exp2f(m - mn);
            m = mn;
            lsum *= al;
#pragma unroll
            for (int r = 0; r < 16; ++r) {
                float a = __shfl(al, (r & 3) + 8 * (r >> 2) + 4 * lh);
                O0[r] *= a;
                O1[r] *= a;
            }
        }

        // ---- P = exp2(S - m) (vectorized sub -> v_pk); l accumulation ----
        s0 = s0 - m;
        s1 = s1 - m;
#pragma unroll
        for (int r = 0; r < 16; ++r) {
            s0[r] = exp2f(s0[r]);
            s1[r] = exp2f(s1[r]);
        }
        {
            f32x16 sv = s0 + s1;  // packed adds
            float p0 = 0.f, p1 = 0.f;
#pragma unroll
            for (int r = 0; r < 16; r += 4) {
                p0 += sv[r] + sv[r + 1];
                p1 += sv[r + 2] + sv[r + 3];
            }
            lsum += p0 + p1;
        }

        // ---- P -> PV A-frags: cvt_pk + permlane32_swap (in-register) ----
        unsigned W0 = cvtpk(s0[0], s0[1]), W1 = cvtpk(s0[2], s0[3]);
        unsigned W2 = cvtpk(s0[4], s0[5]), W3 = cvtpk(s0[6], s0[7]);
        unsigned W4 = cvtpk(s0[8], s0[9]), W5 = cvtpk(s0[10], s0[11]);
        unsigned W6 = cvtpk(s0[12], s0[13]), W7 = cvtpk(s0[14], s0[15]);
        u32x2 rA = plswap(W0, W2), rB = plswap(W1, W3);
        u32x2 rC = plswap(W4, W6), rD = plswap(W5, W7);
        bf16x8 p00 = __builtin_bit_cast(bf16x8, (u32x4){rA.x, rB.x, rA.y, rB.y});
        bf16x8 p01 = __builtin_bit_cast(bf16x8, (u32x4){rC.x, rD.x, rC.y, rD.y});
        W0 = cvtpk(s1[0], s1[1]); W1 = cvtpk(s1[2], s1[3]);
        W2 = cvtpk(s1[4], s1[5]); W3 = cvtpk(s1[6], s1[7]);
        W4 = cvtpk(s1[8], s1[9]); W5 = cvtpk(s1[10], s1[11]);
        W6 = cvtpk(s1[12], s1[13]); W7 = cvtpk(s1[14], s1[15]);
        rA = plswap(W0, W2); rB = plswap(W1, W3);
        rC = plswap(W4, W6); rD = plswap(W5, W7);
        bf16x8 p10 = __builtin_bit_cast(bf16x8, (u32x4){rA.x, rB.x, rA.y, rB.y});
        bf16x8 p11 = __builtin_bit_cast(bf16x8, (u32x4){rC.x, rD.x, rC.y, rD.y});

        // ---- O += P V (operands already in registers) ----
        O0 = MFMA32(p00, v00, O0);
        O0 = MFMA32(p01, v01, O0);
        O0 = MFMA32(p10, v10, O0);
        O0 = MFMA32(p11, v11, O0);
        O1 = MFMA32(p00, w00, O1);
        O1 = MFMA32(p01, w01, O1);
        O1 = MFMA32(p10, w10, O1);
        O1 = MFMA32(p11, w11, O1);

        kh_p += 4 * 8192;   // next owned tile (stride 4)
        kl_p += 4 * 8192;
        vt_p += 4 * 8192;
    }

    // ---- combine the 4 split-KV partials (flash merge in LDS) ----
    if (lh == 0) mlb[wave][0][lq] = m;
    __syncthreads();
    float mstar = fmaxf(fmaxf(mlb[0][0][lq], mlb[1][0][lq]),
                        fmaxf(mlb[2][0][lq], mlb[3][0][lq]));
    float sc = exp2f(m - mstar);
    float lp = xhalf_add(lsum) * sc;
#pragma unroll
    for (int r = 0; r < 16; ++r) {
        float a = __shfl(sc, (r & 3) + 8 * (r >> 2) + 4 * lh);
        O0[r] *= a;
        O1[r] *= a;
    }
    if (wave > 0) {
        if (lh == 0) mlb[wave][1][lq] = lp;
        float* cb = &cbuf[wave - 1][lane][0];
#pragma unroll
        for (int r = 0; r < 16; ++r) {
            cb[r] = O0[r];
            cb[16 + r] = O1[r];
        }
    }
    __syncthreads();
    if (wave == 0) {
        float ltot = lp + mlb[1][1][lq] + mlb[2][1][lq] + mlb[3][1][lq];
#pragma unroll
        for (int i = 0; i < 3; ++i) {
            const float* cb = &cbuf[i][lane][0];
#pragma unroll
            for (int r = 0; r < 16; ++r) {
                O0[r] += cb[r];
                O1[r] += cb[16 + r];
            }
        }
        float linv = 1.0f / ltot;
#pragma unroll
        for (int r = 0; r < 16; ++r) {
            int rr = (r & 3) + 8 * (r >> 2) + 4 * lh;
            float li = __shfl(linv, rr);
            size_t o = hoff + (size_t)(rowbase + rr) * DK + lq;
            out[o] = O0[r] * li;
            out[o + 32] = O1[r] * li;
        }
    }
}

// ---------------------------------------------------------------------------
extern "C" void kernel_launch(void* const* d_in, const int* in_sizes, int n_in,
                              void* d_out, int out_size, void* d_ws, size_t ws_size,
                              hipStream_t stream) {
    const float* x = (const float*)d_in[0];
    const float* qp = (const float*)d_in[1];
    const float* kp = (const float*)d_in[2];
    const float* vp = (const float*)d_in[3];
    float* out = (float*)d_out;

    const size_t WT_SZ = (size_t)NH * DK * E * 2;     // 1,179,648 B
    const size_t QKV_SZ = (size_t)NH * SEQ * DK * 2;  // 6,291,456 B
    const size_t X_SZ = (size_t)SEQ * E * 2;          // 6,291,456 B
    char* ws = (char*)d_ws;
    __bf16* wtq_h = (__bf16*)(ws + 0 * WT_SZ);
    __bf16* wtq_l = (__bf16*)(ws + 1 * WT_SZ);
    __bf16* wtk_h = (__bf16*)(ws + 2 * WT_SZ);
    __bf16* wtk_l = (__bf16*)(ws + 3 * WT_SZ);
    __bf16* wtv_h = (__bf16*)(ws + 4 * WT_SZ);
    char* p2 = ws + 5 * WT_SZ;
    __bf16* qh = (__bf16*)(p2 + 0 * QKV_SZ);
    __bf16* ql = (__bf16*)(p2 + 1 * QKV_SZ);
    __bf16* kh = (__bf16*)(p2 + 2 * QKV_SZ);
    __bf16* kl = (__bf16*)(p2 + 3 * QKV_SZ);
    __bf16* vt = (__bf16*)(p2 + 4 * QKV_SZ);
    char* p3 = p2 + 5 * QKV_SZ;
    __bf16* xh = (__bf16*)(p3 + 0 * X_SZ);
    __bf16* xl = (__bf16*)(p3 + 1 * X_SZ);

    hipLaunchKernelGGL(xsplit_kernel, dim3(SEQ * E / 4 / 256), dim3(256), 0, stream,
                       x, xh, xl);
    hipLaunchKernelGGL(wsplit_kernel, dim3((NH * E * DK + 255) / 256), dim3(256), 0, stream,
                       qp, kp, vp, wtq_h, wtq_l, wtk_h, wtk_l, wtv_h);
    hipLaunchKernelGGL(proj_qk_kernel, dim3(768), dim3(256), 0, stream,
                       xh, xl, wtq_h, wtq_l, wtk_h, wtk_l, qh, ql, kh, kl);
    hipLaunchKernelGGL(proj_v_kernel, dim3(768), dim3(256), 0, stream,
                       xh, wtv_h, vt);
    hipLaunchKernelGGL(attn_kernel, dim3(1536), dim3(256), 0, stream,
                       qh, ql, kh, kl, vt, out);
}